// Round 9
// baseline (56243.445 us; speedup 1.0000x reference)
//
#include <hip/hip_runtime.h>
#include <math.h>

// LSTMNN: T=1024, B=64, I=128, H=512, L=2, fp32. Persistent 256 WG x 1024 thr.
// Round 13: occupancy 2->4 waves/SIMD; everything else = R9 (best, 17.26ms).
//   R12 post-mortem: read-order rotation tripled WRITE_SIZE with identical
//   stores -> scratch-spill signature (runtime chunk index defeated the
//   allocator at the 128-VGPR cap). Discarded. Model correction: R9's
//   FETCH=1.1MB/tick proves the L2 broadcast ALREADY works (misses would be
//   64MB/tick); the residual gap is exposed latency at 2 waves/SIMD
//   (Occupancy 24.8% = one 512-thr WG per CU) + the barrier chain.
//   R13: 1024-thr WGs (16 waves, 4/SIMD), same 256 WGs, same ownership:
//   - thread (s=tid>>4, t4=tid&15): per chunk ONE dense f32x4 load
//     (4 k-rows x 256B fully covered per wave-instr).
//   - acc 128->64 floats; row-quarter blocking (wr[4]) keeps live regs
//     ~120 <= 128 cap (launch_bounds(1024,4)). No spill expected.
//   - reduction: 2 shuffle steps (xor16/32) then 16-wave LDS matrix (64KB).
//   - VALU cycles per SIMD unchanged; latency hiding doubles; phases
//     (loads, LDS, store drain, barrier) overlap across 4 waves.
//   Kept from R9: 8-slot rotation, 7-periodic pre-arrival agent fence,
//   arrive/window/wait split, sc0sc1 write-through stores, monotonic
//   padded 2-level barrier, no per-tick cache maintenance.

namespace {
constexpr int T_STEPS = 1024;
constexpr int B = 64;
constexpr int I_DIM = 128;
constexpr int H = 512;
constexpr int NBLK = 256;
constexpr int NTHR = 1024;     // 16 waves
constexpr int INIT_THR = 512;
constexpr int HB = H * B;   // 32768 floats = 128 KB
constexpr int NSLOT = 8;    // rotation depth
constexpr int P = 20;       // padded chunk dim for LDS weights

// ws layout (floats): 3 rotated streams + biases + barrier
constexpr int OFF_INP  = 0;                      // [8][512][64]
constexpr int OFF_H0   = OFF_INP + NSLOT * HB;   // [8][512][64]
constexpr int OFF_H1   = OFF_H0 + NSLOT * HB;    // [8][512][64]
constexpr int OFF_BSUM = OFF_H1 + NSLOT * HB;    // [2][2048] b_ih+b_hh
constexpr int OFF_BAR  = OFF_BSUM + 2 * 4 * H;   // barrier state
// barrier slots, stride 64 uints (256B): [0..15] group arrivals,
// [16] master, [17..32] per-group release flags, [33] poison
constexpr int BAR_SLOTS = 34;
constexpr int BAR_UINTS = BAR_SLOTS * 64;  // 2176
}  // namespace

typedef float f32x4 __attribute__((ext_vector_type(4)));

// coherent write-through store (sc0 sc1): lands at the coherence point,
// no dirty L2 line anywhere.
__device__ __forceinline__ void coh_store1(float* p, float v) {
  asm volatile("global_store_dword %0, %1, off sc0 sc1" ::"v"(p), "v"(v)
               : "memory");
}

__global__ __launch_bounds__(INIT_THR) void init_ws_kernel(
    float* __restrict__ ws, const float* __restrict__ b_ih,
    const float* __restrict__ b_hh) {
  int idx = blockIdx.x * blockDim.x + threadIdx.x;
  for (int f = idx; f < OFF_BSUM; f += NBLK * INIT_THR) coh_store1(ws + f, 0.f);
  if (idx < 2 * 4 * H) coh_store1(ws + OFF_BSUM + idx, b_ih[idx] + b_hh[idx]);
  if (idx < BAR_UINTS) coh_store1(ws + OFF_BAR + idx, 0.f);  // bits == 0u
}

__device__ __forceinline__ float sigm(float x) {
  return 1.f / (1.f + __expf(-x));
}
__device__ __forceinline__ float tanh_fast(float x) {
  float e = __expf(-2.f * fabsf(x));
  float t = (1.f - e) / (1.f + e);
  return x < 0.f ? -t : t;
}

__global__ __launch_bounds__(NTHR, 4) void lstm_kernel(
    const float* __restrict__ x, const float* __restrict__ w_in,
    const float* __restrict__ b_in, const float* __restrict__ w_ih,
    const float* __restrict__ w_hh, const float* __restrict__ w_out,
    const float* __restrict__ b_out, float* __restrict__ ws,
    float* __restrict__ out) {
  __shared__ float s_w[16 * 64 * P];  // 80 KB persistent gate weights
  __shared__ float s_red[16 * 1024];  // 64 KB reduction matrix (16 waves)
  __shared__ float s_g[1024];         // 4 KB gate pre-activations
  __shared__ float s_h1[512];         // 2 KB gathered h1 column (out)

  const int tid = threadIdx.x;
  const int wg = blockIdx.x;
  const int layer = wg & 1;
  const int lid = wg >> 1;  // 0..127: owns h-columns lid*4 .. +3
  unsigned* const bar = reinterpret_cast<unsigned*>(ws + OFF_BAR);

  // ---- persistent weight load: s_w[(r*64+ss)*P + c] = W[layer][grow][k],
  //      r = q*4+j (q=gate, j=col-within-4), grow = q*512 + lid*4 + j,
  //      k = c*64 + ss (K-concat: k<512 -> w_ih, else w_hh) ----
#pragma unroll
  for (int i = 0; i < 4; ++i) {
    int idx = i * 1024 + tid;  // float4 unit 0..4095
    int r = idx >> 8;          // 0..15
    int k0 = (idx & 255) * 4;
    int grow = (r >> 2) * 512 + lid * 4 + (r & 3);
    const float* srcp =
        (k0 < 512) ? (w_ih + ((size_t)layer * 4 * H + grow) * H + k0)
                   : (w_hh + ((size_t)layer * 4 * H + grow) * H + (k0 - 512));
    float4 v = *reinterpret_cast<const float4*>(srcp);
    float arr[4] = {v.x, v.y, v.z, v.w};
#pragma unroll
    for (int j = 0; j < 4; ++j) {
      int k = k0 + j;
      int c = k >> 6, ss = k & 63;
      s_w[(r * 64 + ss) * P + c] = arr[j];
    }
  }
  __syncthreads();

  // ---- split grid barrier: arrive (with optional pre-arrival L1+L2 inv),
  //      then window work, then wait ----
  unsigned bar_gen = 0;
  auto bar_arrive = [&](bool inv_l2) {
    ++bar_gen;
    if (inv_l2 && tid < 64) {
      // agent acquire: s_waitcnt + buffer_inv (L1+L2). Completes before
      // this WG's arrival (syncthreads below drains wave0's vmcnt).
      __builtin_amdgcn_fence(__ATOMIC_ACQUIRE, "agent");
    }
    __syncthreads();  // drains vmcnt per wave: all sc0sc1 data stores are
                      // at the coherence point before the leader signs in
    if (tid == 0) {
      if (__hip_atomic_load(bar + 33 * 64, __ATOMIC_RELAXED,
                            __HIP_MEMORY_SCOPE_AGENT) == 0u) {
        const unsigned grp = (unsigned)wg & 15u;
        unsigned prev = __hip_atomic_fetch_add(
            bar + grp * 64, 1u, __ATOMIC_RELAXED, __HIP_MEMORY_SCOPE_AGENT);
        if ((prev & 15u) == 15u) {  // last of group (monotonic count)
          unsigned mprev = __hip_atomic_fetch_add(
              bar + 16 * 64, 1u, __ATOMIC_RELAXED, __HIP_MEMORY_SCOPE_AGENT);
          if ((mprev & 15u) == 15u) {  // last group: release everyone
#pragma unroll
            for (int g2 = 0; g2 < 16; ++g2)
              __hip_atomic_store(bar + (17 + g2) * 64, bar_gen,
                                 __ATOMIC_RELAXED, __HIP_MEMORY_SCOPE_AGENT);
          }
        }
      }
    }
  };
  auto bar_wait = [&]() {
    if (tid == 0) {
      if (__hip_atomic_load(bar + 33 * 64, __ATOMIC_RELAXED,
                            __HIP_MEMORY_SCOPE_AGENT) == 0u) {
        const unsigned grp = (unsigned)wg & 15u;
        unsigned spin = 0;
        while (__hip_atomic_load(bar + (17 + grp) * 64, __ATOMIC_RELAXED,
                                 __HIP_MEMORY_SCOPE_AGENT) < bar_gen) {
          __builtin_amdgcn_s_sleep(1);
          if ((++spin & 255u) == 0u) {
            if (__hip_atomic_load(bar + 33 * 64, __ATOMIC_RELAXED,
                                  __HIP_MEMORY_SCOPE_AGENT) != 0u)
              break;
            if (spin > (1u << 19)) {  // failsafe: fast-fail, don't hang
              __hip_atomic_store(bar + 33 * 64, 1u, __ATOMIC_RELAXED,
                                 __HIP_MEMORY_SCOPE_AGENT);
              break;
            }
          }
        }
      }
    }
    __syncthreads();
    // no per-tick cache maintenance (R9 result); staleness covered by the
    // 7-periodic agent fence (reuse distance 8 for all streams).
    asm volatile("" ::: "memory");
  };

  // ---- gates gemv: 16 rows x 64 b, K=1024 = [lo(512);hi(512)], k-major.
  //      Thread (s=tid>>4, t4=tid&15): 16 k-values x 16 rows x 4 batches.
  //      One dense f32x4 per chunk; acc[64]; row-quarter blocking. ----
  auto gemv = [&](const float* __restrict__ lo, const float* __restrict__ hi) {
    const int s = tid >> 4;   // k-slice 0..63
    const int t4 = tid & 15;  // batch quad
    const int abase = s * 64 + t4 * 4;
    float acc[64];            // [row 0..15][bb 0..3]
#pragma unroll
    for (int q = 0; q < 64; ++q) acc[q] = 0.f;

    f32x4 a_cur[4], a_nxt[4];
#pragma unroll
    for (int c = 0; c < 4; ++c)
      a_cur[c] = *reinterpret_cast<const f32x4*>(lo + c * 4096 + abase);
#pragma unroll
    for (int g = 0; g < 4; ++g) {
      if (g < 3) {
#pragma unroll
        for (int cc = 0; cc < 4; ++cc) {
          const int c = (g + 1) * 4 + cc;
          const float* p =
              (c < 8 ? lo + c * 4096 : hi + (c - 8) * 4096) + abase;
          a_nxt[cc] = *reinterpret_cast<const f32x4*>(p);
        }
      }
      // rows in quarters of 4 to cap live wr[] registers (~16)
#pragma unroll
      for (int rh = 0; rh < 4; ++rh) {
        float4 wr[4];
#pragma unroll
        for (int r4 = 0; r4 < 4; ++r4)
          wr[r4] = *reinterpret_cast<const float4*>(
              &s_w[((rh * 4 + r4) * 64 + s) * P + g * 4]);
#pragma unroll
        for (int cc = 0; cc < 4; ++cc) {
          const float a0 = a_cur[cc].x, a1 = a_cur[cc].y, a2 = a_cur[cc].z,
                      a3 = a_cur[cc].w;
#pragma unroll
          for (int r4 = 0; r4 < 4; ++r4) {
            const float w = (cc == 0)   ? wr[r4].x
                            : (cc == 1) ? wr[r4].y
                            : (cc == 2) ? wr[r4].z
                                        : wr[r4].w;
            const int ab = (rh * 4 + r4) * 4;
            acc[ab + 0] = fmaf(w, a0, acc[ab + 0]);
            acc[ab + 1] = fmaf(w, a1, acc[ab + 1]);
            acc[ab + 2] = fmaf(w, a2, acc[ab + 2]);
            acc[ab + 3] = fmaf(w, a3, acc[ab + 3]);
          }
        }
      }
      if (g < 3) {
#pragma unroll
        for (int cc = 0; cc < 4; ++cc) a_cur[cc] = a_nxt[cc];
      }
    }

    // ---- in-wave reduction over lane bits 4,5 (s&3) ----
    const int lane = tid & 63;
    const bool b4 = (lane & 16) != 0;
    const bool b5 = (lane & 32) != 0;
    float v1[32];
#pragma unroll
    for (int go = 0; go < 8; ++go)
#pragma unroll
      for (int bb = 0; bb < 4; ++bb) {
        float lc = acc[(2 * go + 0) * 4 + bb];
        float hc = acc[(2 * go + 1) * 4 + bb];
        float lo_o = __shfl_xor(lc, 16, 64);
        float hi_o = __shfl_xor(hc, 16, 64);
        v1[go * 4 + bb] = b4 ? (hc + hi_o) : (lc + lo_o);
      }
    float fin[16];
#pragma unroll
    for (int go = 0; go < 4; ++go)
#pragma unroll
      for (int bb = 0; bb < 4; ++bb) {
        float lc = v1[(2 * go + 0) * 4 + bb];
        float hc = v1[(2 * go + 1) * 4 + bb];
        float lo_o = __shfl_xor(lc, 32, 64);
        float hi_o = __shfl_xor(hc, 32, 64);
        fin[go * 4 + bb] = b5 ? (hc + hi_o) : (lc + lo_o);
      }
    // lane holds rows {4*go2 + rbase} for b = t4*4..+3,
    // rbase = 2*b5 + b4 (from the two halving steps).
    const int wv = tid >> 6;
    const int rbase = ((lane >> 5) & 1) * 2 + ((lane >> 4) & 1);
#pragma unroll
    for (int go2 = 0; go2 < 4; ++go2) {
      const int row = go2 * 4 + rbase;
      *reinterpret_cast<float4*>(&s_red[wv * 1024 + row * 64 + t4 * 4]) =
          make_float4(fin[go2 * 4 + 0], fin[go2 * 4 + 1], fin[go2 * 4 + 2],
                      fin[go2 * 4 + 3]);
    }
    __syncthreads();
    {
      const float* bsum_l = ws + OFF_BSUM + layer * 2048;
      // o = tid: row = o>>6 (0..15), b = o&63
      float sum = 0.f;
#pragma unroll
      for (int w16 = 0; w16 < 16; ++w16) sum += s_red[w16 * 1024 + tid];
      int r = tid >> 6;
      int grow = (r >> 2) * 512 + lid * 4 + (r & 3);
      s_g[tid] = sum + bsum_l[grow];  // s_g[r*64 + b]
    }
    __syncthreads();
  };

  float cs = 0.f;  // tid<256 owns cell state (col = lid*4 + (tid>>6), b)

  auto cell_update = [&](float* dst) {
    if (tid < 256) {
      const int j = tid >> 6, b = tid & 63, col = lid * 4 + j;
      float ig = sigm(s_g[j * 64 + b]);
      float fg = sigm(s_g[(4 + j) * 64 + b]);
      float gt = tanh_fast(s_g[(8 + j) * 64 + b]);
      float og = sigm(s_g[(12 + j) * 64 + b]);
      cs = fg * cs + ig * gt;
      coh_store1(dst + col * 64 + b, og * tanh_fast(cs));
    }
  };

  // ---- inp(tn) = sigmoid(x[tn] @ w_in^T + b_in) -> cols lid*4..+3 ----
  auto inp_block = [&](int tn, int slot) {
    const int b = tid & 63, jj = (tid >> 6) & 3, kh = tid >> 8;  // kh 0..3
    const int col = lid * 4 + jj;
    const float* xsrc = x + ((size_t)tn * B + b) * I_DIM + kh * 32;
    const float* wrow = w_in + (size_t)col * I_DIM + kh * 32;
    float part = 0.f;
#pragma unroll
    for (int k4 = 0; k4 < 8; ++k4) {
      float4 xv = *reinterpret_cast<const float4*>(xsrc + k4 * 4);
      float4 wv = *reinterpret_cast<const float4*>(wrow + k4 * 4);
      part += xv.x * wv.x + xv.y * wv.y + xv.z * wv.z + xv.w * wv.w;
    }
    s_red[tid] = part;  // layout: kh*256 + jj*64 + b == tid
    __syncthreads();
    if (tid < 256) {
      float v = s_red[tid] + s_red[tid + 256] + s_red[tid + 512] +
                s_red[tid + 768];
      const int jj2 = (tid >> 6) & 3, b2 = tid & 63;
      const int col2 = lid * 4 + jj2;
      coh_store1(ws + OFF_INP + (size_t)slot * HB + col2 * 64 + b2,
                 sigm(v + b_in[col2]));
    }
    __syncthreads();
  };

  // ---- out(tt): gather h1 column b into LDS once, then reduce ----
  auto out_block = [&](int tt, int slot) {
    const int b = lid >> 1, ihalf = lid & 1;
    if (tid < 512)
      s_h1[tid] = ws[OFF_H1 + (size_t)slot * HB + tid * 64 + b];  // cached
    __syncthreads();
    const int io = tid & 63, ks = tid >> 6;  // ks 0..15, 32 k each
    const int i = ihalf * 64 + io;
    const float* wrow = w_out + (size_t)i * H + ks * 32;
    const float* hl = s_h1 + ks * 32;  // broadcast across io lanes
    float part = 0.f;
#pragma unroll
    for (int k4 = 0; k4 < 8; ++k4) {
      float4 wv = *reinterpret_cast<const float4*>(wrow + k4 * 4);
      part += wv.x * hl[k4 * 4 + 0] + wv.y * hl[k4 * 4 + 1] +
              wv.z * hl[k4 * 4 + 2] + wv.w * hl[k4 * 4 + 3];
    }
    s_red[tid] = part;
    __syncthreads();
    if (tid < 64) {
      float sum = 0.f;
#pragma unroll
      for (int kk = 0; kk < 16; ++kk) sum += s_red[kk * 64 + tid];
      const int ii = ihalf * 64 + tid;
      coh_store1(out + ((size_t)tt * B + b) * I_DIM + ii, sum + b_out[ii]);
    }
    __syncthreads();
  };

  // ---------------- prologue: inp(0), inp(1); barrier B0 (inv) ----------
  if (layer == 0) {
    inp_block(0, 0);
    inp_block(1, 1);
  }
  bar_arrive(true);  // B0: inv barrier (also kills pre-launch stale lines)
  bar_wait();

  // ---------------- pipelined main loop: one barrier per tick -----------
  // tick tau: L0 computes h0(tau); L1 computes h1(tau-1). Window work
  // (between arrive and wait): L0 writes inp(tau+2), L1 writes out(tau-2).
  // Barrier after tick tau is B_{tau+1}; inv when (tau+1)%7==0.
  for (int tau = 0; tau <= T_STEPS + 1; ++tau) {
    const int sl = tau & 7;
    const float* glo;
    const float* ghi;
    float* gdst;
    bool do_g;
    if (layer == 0) {
      glo = ws + OFF_INP + (size_t)sl * HB;                  // inp(tau)
      ghi = ws + OFF_H0 + (size_t)((tau - 1) & 7) * HB;      // h0(tau-1)
      gdst = ws + OFF_H0 + (size_t)sl * HB;                  // h0(tau)
      do_g = (tau < T_STEPS);
    } else {
      glo = ws + OFF_H0 + (size_t)((tau - 1) & 7) * HB;      // h0(tau-1)
      ghi = ws + OFF_H1 + (size_t)((tau - 2) & 7) * HB;      // h1(tau-2)
      gdst = ws + OFF_H1 + (size_t)((tau - 1) & 7) * HB;     // h1(tau-1)
      do_g = (tau >= 1 && tau <= T_STEPS);
    }
    if (do_g) {
      gemv(glo, ghi);
      cell_update(gdst);
    }
    if (tau <= T_STEPS) {
      bar_arrive(((tau + 1) % 7) == 0);
      // ---- window work (post-arrival, pre-release) ----
      if (layer == 0) {
        if (tau + 2 <= T_STEPS - 1) inp_block(tau + 2, (tau + 2) & 7);
      } else {
        if (tau >= 2) out_block(tau - 2, (tau - 2) & 7);
      }
      bar_wait();
    } else {
      // final tick (tau == T_STEPS+1): no barrier; L1 emits last output
      if (layer == 1) out_block(tau - 2, (tau - 2) & 7);
    }
  }
}

extern "C" void kernel_launch(void* const* d_in, const int* in_sizes, int n_in,
                              void* d_out, int out_size, void* d_ws,
                              size_t ws_size, hipStream_t stream) {
  const float* x     = (const float*)d_in[0];
  const float* w_in  = (const float*)d_in[1];
  const float* b_in  = (const float*)d_in[2];
  const float* w_ih  = (const float*)d_in[3];
  const float* w_hh  = (const float*)d_in[4];
  const float* b_ih  = (const float*)d_in[5];
  const float* b_hh  = (const float*)d_in[6];
  const float* w_out = (const float*)d_in[7];
  const float* b_out = (const float*)d_in[8];
  float* ws   = (float*)d_ws;
  float* outp = (float*)d_out;

  hipLaunchKernelGGL(init_ws_kernel, dim3(NBLK), dim3(INIT_THR), 0, stream,
                     ws, b_ih, b_hh);
  hipLaunchKernelGGL(lstm_kernel, dim3(NBLK), dim3(NTHR), 0, stream, x, w_in,
                     b_in, w_ih, w_hh, w_out, b_out, ws, outp);
}

// Round 10
// 50625.992 us; speedup vs baseline: 1.1110x; 1.1110x over previous
//
#include <hip/hip_runtime.h>
#include <math.h>

// LSTMNN: T=1024, B=64, I=128, H=512, L=2, fp32. Persistent 256 WG x 1024 thr.
// Round 14: R13 retried with the CORRECT register budget.
//   R13 post-mortem: __launch_bounds__ 2nd arg is min BLOCKS per CU (CUDA
//   semantics), not waves/EU. (1024,4) asked for 64 waves/CU -> clamped to
//   32 -> 64-VGPR cap (VGPR_Count=64 observed) -> acc[64]+operands spilled
//   to scratch: FETCH 78GB / WRITE 125GB, 56ms. Cross-check: R9's (512,2)
//   = 16 waves/CU = 128 VGPR, as reported. The occupancy theory was never
//   tested. R14: single change -> __launch_bounds__(1024, 1): 1 block/CU =
//   16 waves = 4 waves/SIMD, 128-VGPR cap. Demand ~120 fits (plus unified
//   AGPR slack, which covered R9's acc[128] at the same cap).
//   Validity check in counters: VGPR_Count must read 128 and WRITE_SIZE
//   ~0.45GB; then dur tests the exposed-latency hypothesis cleanly.
//   Kept from R13/R9: ownership (lid owns 4 h-cols), dense f32x4 gemv
//   loads, 2-shuffle + 16-wave LDS reduction, 8-slot rotation, 7-periodic
//   pre-arrival agent fence, arrive/window/wait split, sc0sc1 stores,
//   monotonic padded 2-level barrier, no per-tick cache maintenance.

namespace {
constexpr int T_STEPS = 1024;
constexpr int B = 64;
constexpr int I_DIM = 128;
constexpr int H = 512;
constexpr int NBLK = 256;
constexpr int NTHR = 1024;     // 16 waves
constexpr int INIT_THR = 512;
constexpr int HB = H * B;   // 32768 floats = 128 KB
constexpr int NSLOT = 8;    // rotation depth
constexpr int P = 20;       // padded chunk dim for LDS weights

// ws layout (floats): 3 rotated streams + biases + barrier
constexpr int OFF_INP  = 0;                      // [8][512][64]
constexpr int OFF_H0   = OFF_INP + NSLOT * HB;   // [8][512][64]
constexpr int OFF_H1   = OFF_H0 + NSLOT * HB;    // [8][512][64]
constexpr int OFF_BSUM = OFF_H1 + NSLOT * HB;    // [2][2048] b_ih+b_hh
constexpr int OFF_BAR  = OFF_BSUM + 2 * 4 * H;   // barrier state
// barrier slots, stride 64 uints (256B): [0..15] group arrivals,
// [16] master, [17..32] per-group release flags, [33] poison
constexpr int BAR_SLOTS = 34;
constexpr int BAR_UINTS = BAR_SLOTS * 64;  // 2176
}  // namespace

typedef float f32x4 __attribute__((ext_vector_type(4)));

// coherent write-through store (sc0 sc1): lands at the coherence point,
// no dirty L2 line anywhere.
__device__ __forceinline__ void coh_store1(float* p, float v) {
  asm volatile("global_store_dword %0, %1, off sc0 sc1" ::"v"(p), "v"(v)
               : "memory");
}

__global__ __launch_bounds__(INIT_THR) void init_ws_kernel(
    float* __restrict__ ws, const float* __restrict__ b_ih,
    const float* __restrict__ b_hh) {
  int idx = blockIdx.x * blockDim.x + threadIdx.x;
  for (int f = idx; f < OFF_BSUM; f += NBLK * INIT_THR) coh_store1(ws + f, 0.f);
  if (idx < 2 * 4 * H) coh_store1(ws + OFF_BSUM + idx, b_ih[idx] + b_hh[idx]);
  if (idx < BAR_UINTS) coh_store1(ws + OFF_BAR + idx, 0.f);  // bits == 0u
}

__device__ __forceinline__ float sigm(float x) {
  return 1.f / (1.f + __expf(-x));
}
__device__ __forceinline__ float tanh_fast(float x) {
  float e = __expf(-2.f * fabsf(x));
  float t = (1.f - e) / (1.f + e);
  return x < 0.f ? -t : t;
}

__global__ __launch_bounds__(NTHR, 1) void lstm_kernel(
    const float* __restrict__ x, const float* __restrict__ w_in,
    const float* __restrict__ b_in, const float* __restrict__ w_ih,
    const float* __restrict__ w_hh, const float* __restrict__ w_out,
    const float* __restrict__ b_out, float* __restrict__ ws,
    float* __restrict__ out) {
  __shared__ float s_w[16 * 64 * P];  // 80 KB persistent gate weights
  __shared__ float s_red[16 * 1024];  // 64 KB reduction matrix (16 waves)
  __shared__ float s_g[1024];         // 4 KB gate pre-activations
  __shared__ float s_h1[512];         // 2 KB gathered h1 column (out)

  const int tid = threadIdx.x;
  const int wg = blockIdx.x;
  const int layer = wg & 1;
  const int lid = wg >> 1;  // 0..127: owns h-columns lid*4 .. +3
  unsigned* const bar = reinterpret_cast<unsigned*>(ws + OFF_BAR);

  // ---- persistent weight load: s_w[(r*64+ss)*P + c] = W[layer][grow][k],
  //      r = q*4+j (q=gate, j=col-within-4), grow = q*512 + lid*4 + j,
  //      k = c*64 + ss (K-concat: k<512 -> w_ih, else w_hh) ----
#pragma unroll
  for (int i = 0; i < 4; ++i) {
    int idx = i * 1024 + tid;  // float4 unit 0..4095
    int r = idx >> 8;          // 0..15
    int k0 = (idx & 255) * 4;
    int grow = (r >> 2) * 512 + lid * 4 + (r & 3);
    const float* srcp =
        (k0 < 512) ? (w_ih + ((size_t)layer * 4 * H + grow) * H + k0)
                   : (w_hh + ((size_t)layer * 4 * H + grow) * H + (k0 - 512));
    float4 v = *reinterpret_cast<const float4*>(srcp);
    float arr[4] = {v.x, v.y, v.z, v.w};
#pragma unroll
    for (int j = 0; j < 4; ++j) {
      int k = k0 + j;
      int c = k >> 6, ss = k & 63;
      s_w[(r * 64 + ss) * P + c] = arr[j];
    }
  }
  __syncthreads();

  // ---- split grid barrier: arrive (with optional pre-arrival L1+L2 inv),
  //      then window work, then wait ----
  unsigned bar_gen = 0;
  auto bar_arrive = [&](bool inv_l2) {
    ++bar_gen;
    if (inv_l2 && tid < 64) {
      // agent acquire: s_waitcnt + buffer_inv (L1+L2). Completes before
      // this WG's arrival (syncthreads below drains wave0's vmcnt).
      __builtin_amdgcn_fence(__ATOMIC_ACQUIRE, "agent");
    }
    __syncthreads();  // drains vmcnt per wave: all sc0sc1 data stores are
                      // at the coherence point before the leader signs in
    if (tid == 0) {
      if (__hip_atomic_load(bar + 33 * 64, __ATOMIC_RELAXED,
                            __HIP_MEMORY_SCOPE_AGENT) == 0u) {
        const unsigned grp = (unsigned)wg & 15u;
        unsigned prev = __hip_atomic_fetch_add(
            bar + grp * 64, 1u, __ATOMIC_RELAXED, __HIP_MEMORY_SCOPE_AGENT);
        if ((prev & 15u) == 15u) {  // last of group (monotonic count)
          unsigned mprev = __hip_atomic_fetch_add(
              bar + 16 * 64, 1u, __ATOMIC_RELAXED, __HIP_MEMORY_SCOPE_AGENT);
          if ((mprev & 15u) == 15u) {  // last group: release everyone
#pragma unroll
            for (int g2 = 0; g2 < 16; ++g2)
              __hip_atomic_store(bar + (17 + g2) * 64, bar_gen,
                                 __ATOMIC_RELAXED, __HIP_MEMORY_SCOPE_AGENT);
          }
        }
      }
    }
  };
  auto bar_wait = [&]() {
    if (tid == 0) {
      if (__hip_atomic_load(bar + 33 * 64, __ATOMIC_RELAXED,
                            __HIP_MEMORY_SCOPE_AGENT) == 0u) {
        const unsigned grp = (unsigned)wg & 15u;
        unsigned spin = 0;
        while (__hip_atomic_load(bar + (17 + grp) * 64, __ATOMIC_RELAXED,
                                 __HIP_MEMORY_SCOPE_AGENT) < bar_gen) {
          __builtin_amdgcn_s_sleep(1);
          if ((++spin & 255u) == 0u) {
            if (__hip_atomic_load(bar + 33 * 64, __ATOMIC_RELAXED,
                                  __HIP_MEMORY_SCOPE_AGENT) != 0u)
              break;
            if (spin > (1u << 19)) {  // failsafe: fast-fail, don't hang
              __hip_atomic_store(bar + 33 * 64, 1u, __ATOMIC_RELAXED,
                                 __HIP_MEMORY_SCOPE_AGENT);
              break;
            }
          }
        }
      }
    }
    __syncthreads();
    // no per-tick cache maintenance (R9 result); staleness covered by the
    // 7-periodic agent fence (reuse distance 8 for all streams).
    asm volatile("" ::: "memory");
  };

  // ---- gates gemv: 16 rows x 64 b, K=1024 = [lo(512);hi(512)], k-major.
  //      Thread (s=tid>>4, t4=tid&15): 16 k-values x 16 rows x 4 batches.
  //      One dense f32x4 per chunk; acc[64]; row-quarter blocking. ----
  auto gemv = [&](const float* __restrict__ lo, const float* __restrict__ hi) {
    const int s = tid >> 4;   // k-slice 0..63
    const int t4 = tid & 15;  // batch quad
    const int abase = s * 64 + t4 * 4;
    float acc[64];            // [row 0..15][bb 0..3]
#pragma unroll
    for (int q = 0; q < 64; ++q) acc[q] = 0.f;

    f32x4 a_cur[4], a_nxt[4];
#pragma unroll
    for (int c = 0; c < 4; ++c)
      a_cur[c] = *reinterpret_cast<const f32x4*>(lo + c * 4096 + abase);
#pragma unroll
    for (int g = 0; g < 4; ++g) {
      if (g < 3) {
#pragma unroll
        for (int cc = 0; cc < 4; ++cc) {
          const int c = (g + 1) * 4 + cc;
          const float* p =
              (c < 8 ? lo + c * 4096 : hi + (c - 8) * 4096) + abase;
          a_nxt[cc] = *reinterpret_cast<const f32x4*>(p);
        }
      }
      // rows in quarters of 4 to cap live wr[] registers (~16)
#pragma unroll
      for (int rh = 0; rh < 4; ++rh) {
        float4 wr[4];
#pragma unroll
        for (int r4 = 0; r4 < 4; ++r4)
          wr[r4] = *reinterpret_cast<const float4*>(
              &s_w[((rh * 4 + r4) * 64 + s) * P + g * 4]);
#pragma unroll
        for (int cc = 0; cc < 4; ++cc) {
          const float a0 = a_cur[cc].x, a1 = a_cur[cc].y, a2 = a_cur[cc].z,
                      a3 = a_cur[cc].w;
#pragma unroll
          for (int r4 = 0; r4 < 4; ++r4) {
            const float w = (cc == 0)   ? wr[r4].x
                            : (cc == 1) ? wr[r4].y
                            : (cc == 2) ? wr[r4].z
                                        : wr[r4].w;
            const int ab = (rh * 4 + r4) * 4;
            acc[ab + 0] = fmaf(w, a0, acc[ab + 0]);
            acc[ab + 1] = fmaf(w, a1, acc[ab + 1]);
            acc[ab + 2] = fmaf(w, a2, acc[ab + 2]);
            acc[ab + 3] = fmaf(w, a3, acc[ab + 3]);
          }
        }
      }
      if (g < 3) {
#pragma unroll
        for (int cc = 0; cc < 4; ++cc) a_cur[cc] = a_nxt[cc];
      }
    }

    // ---- in-wave reduction over lane bits 4,5 (s&3) ----
    const int lane = tid & 63;
    const bool b4 = (lane & 16) != 0;
    const bool b5 = (lane & 32) != 0;
    float v1[32];
#pragma unroll
    for (int go = 0; go < 8; ++go)
#pragma unroll
      for (int bb = 0; bb < 4; ++bb) {
        float lc = acc[(2 * go + 0) * 4 + bb];
        float hc = acc[(2 * go + 1) * 4 + bb];
        float lo_o = __shfl_xor(lc, 16, 64);
        float hi_o = __shfl_xor(hc, 16, 64);
        v1[go * 4 + bb] = b4 ? (hc + hi_o) : (lc + lo_o);
      }
    float fin[16];
#pragma unroll
    for (int go = 0; go < 4; ++go)
#pragma unroll
      for (int bb = 0; bb < 4; ++bb) {
        float lc = v1[(2 * go + 0) * 4 + bb];
        float hc = v1[(2 * go + 1) * 4 + bb];
        float lo_o = __shfl_xor(lc, 32, 64);
        float hi_o = __shfl_xor(hc, 32, 64);
        fin[go * 4 + bb] = b5 ? (hc + hi_o) : (lc + lo_o);
      }
    // lane holds rows {4*go2 + rbase} for b = t4*4..+3,
    // rbase = 2*b5 + b4 (from the two halving steps).
    const int wv = tid >> 6;
    const int rbase = ((lane >> 5) & 1) * 2 + ((lane >> 4) & 1);
#pragma unroll
    for (int go2 = 0; go2 < 4; ++go2) {
      const int row = go2 * 4 + rbase;
      *reinterpret_cast<float4*>(&s_red[wv * 1024 + row * 64 + t4 * 4]) =
          make_float4(fin[go2 * 4 + 0], fin[go2 * 4 + 1], fin[go2 * 4 + 2],
                      fin[go2 * 4 + 3]);
    }
    __syncthreads();
    {
      const float* bsum_l = ws + OFF_BSUM + layer * 2048;
      // o = tid: row = o>>6 (0..15), b = o&63
      float sum = 0.f;
#pragma unroll
      for (int w16 = 0; w16 < 16; ++w16) sum += s_red[w16 * 1024 + tid];
      int r = tid >> 6;
      int grow = (r >> 2) * 512 + lid * 4 + (r & 3);
      s_g[tid] = sum + bsum_l[grow];  // s_g[r*64 + b]
    }
    __syncthreads();
  };

  float cs = 0.f;  // tid<256 owns cell state (col = lid*4 + (tid>>6), b)

  auto cell_update = [&](float* dst) {
    if (tid < 256) {
      const int j = tid >> 6, b = tid & 63, col = lid * 4 + j;
      float ig = sigm(s_g[j * 64 + b]);
      float fg = sigm(s_g[(4 + j) * 64 + b]);
      float gt = tanh_fast(s_g[(8 + j) * 64 + b]);
      float og = sigm(s_g[(12 + j) * 64 + b]);
      cs = fg * cs + ig * gt;
      coh_store1(dst + col * 64 + b, og * tanh_fast(cs));
    }
  };

  // ---- inp(tn) = sigmoid(x[tn] @ w_in^T + b_in) -> cols lid*4..+3 ----
  auto inp_block = [&](int tn, int slot) {
    const int b = tid & 63, jj = (tid >> 6) & 3, kh = tid >> 8;  // kh 0..3
    const int col = lid * 4 + jj;
    const float* xsrc = x + ((size_t)tn * B + b) * I_DIM + kh * 32;
    const float* wrow = w_in + (size_t)col * I_DIM + kh * 32;
    float part = 0.f;
#pragma unroll
    for (int k4 = 0; k4 < 8; ++k4) {
      float4 xv = *reinterpret_cast<const float4*>(xsrc + k4 * 4);
      float4 wv = *reinterpret_cast<const float4*>(wrow + k4 * 4);
      part += xv.x * wv.x + xv.y * wv.y + xv.z * wv.z + xv.w * wv.w;
    }
    s_red[tid] = part;  // layout: kh*256 + jj*64 + b == tid
    __syncthreads();
    if (tid < 256) {
      float v = s_red[tid] + s_red[tid + 256] + s_red[tid + 512] +
                s_red[tid + 768];
      const int jj2 = (tid >> 6) & 3, b2 = tid & 63;
      const int col2 = lid * 4 + jj2;
      coh_store1(ws + OFF_INP + (size_t)slot * HB + col2 * 64 + b2,
                 sigm(v + b_in[col2]));
    }
    __syncthreads();
  };

  // ---- out(tt): gather h1 column b into LDS once, then reduce ----
  auto out_block = [&](int tt, int slot) {
    const int b = lid >> 1, ihalf = lid & 1;
    if (tid < 512)
      s_h1[tid] = ws[OFF_H1 + (size_t)slot * HB + tid * 64 + b];  // cached
    __syncthreads();
    const int io = tid & 63, ks = tid >> 6;  // ks 0..15, 32 k each
    const int i = ihalf * 64 + io;
    const float* wrow = w_out + (size_t)i * H + ks * 32;
    const float* hl = s_h1 + ks * 32;  // broadcast across io lanes
    float part = 0.f;
#pragma unroll
    for (int k4 = 0; k4 < 8; ++k4) {
      float4 wv = *reinterpret_cast<const float4*>(wrow + k4 * 4);
      part += wv.x * hl[k4 * 4 + 0] + wv.y * hl[k4 * 4 + 1] +
              wv.z * hl[k4 * 4 + 2] + wv.w * hl[k4 * 4 + 3];
    }
    s_red[tid] = part;
    __syncthreads();
    if (tid < 64) {
      float sum = 0.f;
#pragma unroll
      for (int kk = 0; kk < 16; ++kk) sum += s_red[kk * 64 + tid];
      const int ii = ihalf * 64 + tid;
      coh_store1(out + ((size_t)tt * B + b) * I_DIM + ii, sum + b_out[ii]);
    }
    __syncthreads();
  };

  // ---------------- prologue: inp(0), inp(1); barrier B0 (inv) ----------
  if (layer == 0) {
    inp_block(0, 0);
    inp_block(1, 1);
  }
  bar_arrive(true);  // B0: inv barrier (also kills pre-launch stale lines)
  bar_wait();

  // ---------------- pipelined main loop: one barrier per tick -----------
  // tick tau: L0 computes h0(tau); L1 computes h1(tau-1). Window work
  // (between arrive and wait): L0 writes inp(tau+2), L1 writes out(tau-2).
  // Barrier after tick tau is B_{tau+1}; inv when (tau+1)%7==0.
  for (int tau = 0; tau <= T_STEPS + 1; ++tau) {
    const int sl = tau & 7;
    const float* glo;
    const float* ghi;
    float* gdst;
    bool do_g;
    if (layer == 0) {
      glo = ws + OFF_INP + (size_t)sl * HB;                  // inp(tau)
      ghi = ws + OFF_H0 + (size_t)((tau - 1) & 7) * HB;      // h0(tau-1)
      gdst = ws + OFF_H0 + (size_t)sl * HB;                  // h0(tau)
      do_g = (tau < T_STEPS);
    } else {
      glo = ws + OFF_H0 + (size_t)((tau - 1) & 7) * HB;      // h0(tau-1)
      ghi = ws + OFF_H1 + (size_t)((tau - 2) & 7) * HB;      // h1(tau-2)
      gdst = ws + OFF_H1 + (size_t)((tau - 1) & 7) * HB;     // h1(tau-1)
      do_g = (tau >= 1 && tau <= T_STEPS);
    }
    if (do_g) {
      gemv(glo, ghi);
      cell_update(gdst);
    }
    if (tau <= T_STEPS) {
      bar_arrive(((tau + 1) % 7) == 0);
      // ---- window work (post-arrival, pre-release) ----
      if (layer == 0) {
        if (tau + 2 <= T_STEPS - 1) inp_block(tau + 2, (tau + 2) & 7);
      } else {
        if (tau >= 2) out_block(tau - 2, (tau - 2) & 7);
      }
      bar_wait();
    } else {
      // final tick (tau == T_STEPS+1): no barrier; L1 emits last output
      if (layer == 1) out_block(tau - 2, (tau - 2) & 7);
    }
  }
}

extern "C" void kernel_launch(void* const* d_in, const int* in_sizes, int n_in,
                              void* d_out, int out_size, void* d_ws,
                              size_t ws_size, hipStream_t stream) {
  const float* x     = (const float*)d_in[0];
  const float* w_in  = (const float*)d_in[1];
  const float* b_in  = (const float*)d_in[2];
  const float* w_ih  = (const float*)d_in[3];
  const float* w_hh  = (const float*)d_in[4];
  const float* b_ih  = (const float*)d_in[5];
  const float* b_hh  = (const float*)d_in[6];
  const float* w_out = (const float*)d_in[7];
  const float* b_out = (const float*)d_in[8];
  float* ws   = (float*)d_ws;
  float* outp = (float*)d_out;

  hipLaunchKernelGGL(init_ws_kernel, dim3(NBLK), dim3(INIT_THR), 0, stream,
                     ws, b_ih, b_hh);
  hipLaunchKernelGGL(lstm_kernel, dim3(NBLK), dim3(NTHR), 0, stream, x, w_in,
                     b_in, w_ih, w_hh, w_out, b_out, ws, outp);
}

// Round 11
// 17418.532 us; speedup vs baseline: 3.2289x; 2.9064x over previous
//
#include <hip/hip_runtime.h>
#include <math.h>

// LSTMNN: T=1024, B=64, I=128, H=512, L=2, fp32. Persistent 256 WG x 512 thr.
// Round 15: R9 (best, 17.26ms) with the workspace moved from d_ws to a
// __device__ module-global buffer.
//   R14 post-mortem: 1024-thr WGs pin VGPR=64 on this toolchain regardless
//   of launch-bounds (2 interpretations tried) -> big-block occupancy lever
//   abandoned. Deeper re-read: FETCH_SIZE counts HBM only (MALL-invisible),
//   so R9's small FETCH never proved L2 reuse. R4 (sc0sc1 bypass reads) and
//   R9 (plain reads) stream at the SAME ~3.7TB/s -> plain loads behave like
//   L2-bypass loads. Hypothesis: d_ws is fine-grained (host-visible) memory,
//   uncacheable at L2, MALL-served only — explains 9 rounds of fence-policy
//   invariance, the 3.6-3.9TB/s wall, R10/R11 sub-line store anomalies, and
//   why L2-staleness windows never tripped.
//   R15: activations/biases/barrier live in __device__ g_ws (loader-
//   allocated device memory, coarse-grained, L2-cacheable). d_ws ignored.
//   init_ws_kernel re-zeroes g_ws every launch (replaces harness ws reset).
//   Correctness with REAL L2 caching re-verified: at an inv barrier every
//   WG's buffer_inv precedes its own arrival -> at release no pre-barrier
//   fill survives on any XCD; fills always come from write-through-fresh
//   MALL; max write->read gap 2 barriers, regeneration distance 8, >=1 inv
//   per 7 barriers. Kept from R9: 8-slot rotation, 7-periodic pre-arrival
//   agent fence, arrive/window/wait split, sc0sc1 write-through stores,
//   monotonic padded 2-level barrier, no per-tick cache maintenance.

namespace {
constexpr int T_STEPS = 1024;
constexpr int B = 64;
constexpr int I_DIM = 128;
constexpr int H = 512;
constexpr int NBLK = 256;
constexpr int NTHR = 512;
constexpr int HB = H * B;   // 32768 floats = 128 KB
constexpr int NSLOT = 8;    // rotation depth
constexpr int P = 20;       // padded chunk dim for LDS weights

// g_ws layout (floats): 3 rotated streams + biases + barrier
constexpr int OFF_INP  = 0;                      // [8][512][64]
constexpr int OFF_H0   = OFF_INP + NSLOT * HB;   // [8][512][64]
constexpr int OFF_H1   = OFF_H0 + NSLOT * HB;    // [8][512][64]
constexpr int OFF_BSUM = OFF_H1 + NSLOT * HB;    // [2][2048] b_ih+b_hh
constexpr int OFF_BAR  = OFF_BSUM + 2 * 4 * H;   // barrier state
// barrier slots, stride 64 uints (256B): [0..15] group arrivals,
// [16] master, [17..32] per-group release flags, [33] poison
constexpr int BAR_SLOTS = 34;
constexpr int BAR_UINTS = BAR_SLOTS * 64;  // 2176
constexpr int WS_FLOATS = OFF_BAR + BAR_UINTS;
}  // namespace

// Module-global workspace: loader-allocated DEVICE memory (coarse-grained,
// L2-cacheable) — the whole point of R15.
__device__ __align__(256) float g_ws[WS_FLOATS];

typedef float f32x4 __attribute__((ext_vector_type(4)));

// coherent write-through store (sc0 sc1): lands at the coherence point,
// no dirty L2 line anywhere.
__device__ __forceinline__ void coh_store1(float* p, float v) {
  asm volatile("global_store_dword %0, %1, off sc0 sc1" ::"v"(p), "v"(v)
               : "memory");
}

__global__ __launch_bounds__(NTHR) void init_ws_kernel(
    const float* __restrict__ b_ih, const float* __restrict__ b_hh) {
  int idx = blockIdx.x * blockDim.x + threadIdx.x;
  for (int f = idx; f < OFF_BSUM; f += NBLK * NTHR) coh_store1(g_ws + f, 0.f);
  if (idx < 2 * 4 * H) coh_store1(g_ws + OFF_BSUM + idx, b_ih[idx] + b_hh[idx]);
  if (idx < BAR_UINTS) coh_store1(g_ws + OFF_BAR + idx, 0.f);  // bits == 0u
}

__device__ __forceinline__ float sigm(float x) {
  return 1.f / (1.f + __expf(-x));
}
__device__ __forceinline__ float tanh_fast(float x) {
  float e = __expf(-2.f * fabsf(x));
  float t = (1.f - e) / (1.f + e);
  return x < 0.f ? -t : t;
}

__global__ __launch_bounds__(NTHR, 2) void lstm_kernel(
    const float* __restrict__ x, const float* __restrict__ w_in,
    const float* __restrict__ b_in, const float* __restrict__ w_ih,
    const float* __restrict__ w_hh, const float* __restrict__ w_out,
    const float* __restrict__ b_out, float* __restrict__ out) {
  __shared__ float s_w[16 * 64 * P];  // 80 KB persistent gate weights
  __shared__ float s_red[8 * 1024];   // 32 KB reduction scratch
  __shared__ float s_g[1024];         // 4 KB gate pre-activations
  __shared__ float s_h1[512];         // 2 KB gathered h1 column (out)

  const int tid = threadIdx.x;
  const int wg = blockIdx.x;
  const int layer = wg & 1;
  const int lid = wg >> 1;  // 0..127: owns h-columns lid*4 .. +3
  unsigned* const bar = reinterpret_cast<unsigned*>(g_ws + OFF_BAR);

  // ---- persistent weight load: s_w[(r*64+ss)*P + c] = W[layer][grow][k],
  //      r = q*4+j (q=gate, j=col-within-4), grow = q*512 + lid*4 + j,
  //      k = c*64 + ss (K-concat: k<512 -> w_ih, else w_hh) ----
#pragma unroll
  for (int i = 0; i < 8; ++i) {
    int idx = i * 512 + tid;  // float4 unit 0..4095
    int r = idx >> 8;         // 0..15
    int k0 = (idx & 255) * 4;
    int grow = (r >> 2) * 512 + lid * 4 + (r & 3);
    const float* srcp =
        (k0 < 512) ? (w_ih + ((size_t)layer * 4 * H + grow) * H + k0)
                   : (w_hh + ((size_t)layer * 4 * H + grow) * H + (k0 - 512));
    float4 v = *reinterpret_cast<const float4*>(srcp);
    float arr[4] = {v.x, v.y, v.z, v.w};
#pragma unroll
    for (int j = 0; j < 4; ++j) {
      int k = k0 + j;
      int c = k >> 6, ss = k & 63;
      s_w[(r * 64 + ss) * P + c] = arr[j];
    }
  }
  __syncthreads();

  // ---- split grid barrier: arrive (with optional pre-arrival L1+L2 inv),
  //      then window work, then wait ----
  unsigned bar_gen = 0;
  auto bar_arrive = [&](bool inv_l2) {
    ++bar_gen;
    if (inv_l2 && tid < 64) {
      // agent acquire: s_waitcnt + buffer_inv (L1+L2). Completes before
      // this WG's arrival (syncthreads below drains wave0's vmcnt).
      __builtin_amdgcn_fence(__ATOMIC_ACQUIRE, "agent");
    }
    __syncthreads();  // drains vmcnt per wave: all sc0sc1 data stores are
                      // at the coherence point before the leader signs in
    if (tid == 0) {
      if (__hip_atomic_load(bar + 33 * 64, __ATOMIC_RELAXED,
                            __HIP_MEMORY_SCOPE_AGENT) == 0u) {
        const unsigned grp = (unsigned)wg & 15u;
        unsigned prev = __hip_atomic_fetch_add(
            bar + grp * 64, 1u, __ATOMIC_RELAXED, __HIP_MEMORY_SCOPE_AGENT);
        if ((prev & 15u) == 15u) {  // last of group (monotonic count)
          unsigned mprev = __hip_atomic_fetch_add(
              bar + 16 * 64, 1u, __ATOMIC_RELAXED, __HIP_MEMORY_SCOPE_AGENT);
          if ((mprev & 15u) == 15u) {  // last group: release everyone
#pragma unroll
            for (int g2 = 0; g2 < 16; ++g2)
              __hip_atomic_store(bar + (17 + g2) * 64, bar_gen,
                                 __ATOMIC_RELAXED, __HIP_MEMORY_SCOPE_AGENT);
          }
        }
      }
    }
  };
  auto bar_wait = [&]() {
    if (tid == 0) {
      if (__hip_atomic_load(bar + 33 * 64, __ATOMIC_RELAXED,
                            __HIP_MEMORY_SCOPE_AGENT) == 0u) {
        const unsigned grp = (unsigned)wg & 15u;
        unsigned spin = 0;
        while (__hip_atomic_load(bar + (17 + grp) * 64, __ATOMIC_RELAXED,
                                 __HIP_MEMORY_SCOPE_AGENT) < bar_gen) {
          __builtin_amdgcn_s_sleep(1);
          if ((++spin & 255u) == 0u) {
            if (__hip_atomic_load(bar + 33 * 64, __ATOMIC_RELAXED,
                                  __HIP_MEMORY_SCOPE_AGENT) != 0u)
              break;
            if (spin > (1u << 19)) {  // failsafe: fast-fail, don't hang
              __hip_atomic_store(bar + 33 * 64, 1u, __ATOMIC_RELAXED,
                                 __HIP_MEMORY_SCOPE_AGENT);
              break;
            }
          }
        }
      }
    }
    __syncthreads();
    // no per-tick cache maintenance (R9 result); staleness covered by the
    // 7-periodic agent fence (reuse distance 8 for all streams).
    asm volatile("" ::: "memory");
  };

  // ---- gates gemv: 16 rows x 64 b, K=1024 = [lo(512);hi(512)], k-major.
  //      Weights from LDS; activations via plain cached loads (now on
  //      L2-cacheable device-global memory). ----
  auto gemv = [&](const float* __restrict__ lo, const float* __restrict__ hi) {
    const int s = tid >> 3;  // k-slice 0..63
    const int tb = tid & 7;  // batch octet
    const int abase = s * 64 + tb * 8;
    float acc[128];
#pragma unroll
    for (int q = 0; q < 128; ++q) acc[q] = 0.f;

    f32x4 a_cur[4][2], a_nxt[4][2];
#pragma unroll
    for (int c = 0; c < 4; ++c) {
      const float* p = lo + c * 4096 + abase;
      a_cur[c][0] = *reinterpret_cast<const f32x4*>(p);
      a_cur[c][1] = *reinterpret_cast<const f32x4*>(p + 4);
    }
#pragma unroll
    for (int g = 0; g < 4; ++g) {
      if (g < 3) {
#pragma unroll
        for (int cc = 0; cc < 4; ++cc) {
          const int c = (g + 1) * 4 + cc;
          const float* p =
              (c < 8 ? lo + c * 4096 : hi + (c - 8) * 4096) + abase;
          a_nxt[cc][0] = *reinterpret_cast<const f32x4*>(p);
          a_nxt[cc][1] = *reinterpret_cast<const f32x4*>(p + 4);
        }
      }
      // rows in two halves of 8 to cap live wr[] registers
#pragma unroll
      for (int rh = 0; rh < 2; ++rh) {
        float4 wr[8];
#pragma unroll
        for (int r8 = 0; r8 < 8; ++r8)
          wr[r8] = *reinterpret_cast<const float4*>(
              &s_w[((rh * 8 + r8) * 64 + s) * P + g * 4]);
#pragma unroll
        for (int cc = 0; cc < 4; ++cc) {
          float av[8] = {a_cur[cc][0].x, a_cur[cc][0].y, a_cur[cc][0].z,
                         a_cur[cc][0].w, a_cur[cc][1].x, a_cur[cc][1].y,
                         a_cur[cc][1].z, a_cur[cc][1].w};
#pragma unroll
          for (int r8 = 0; r8 < 8; ++r8) {
            float w = (cc == 0)   ? wr[r8].x
                      : (cc == 1) ? wr[r8].y
                      : (cc == 2) ? wr[r8].z
                                  : wr[r8].w;
#pragma unroll
            for (int bb = 0; bb < 8; ++bb)
              acc[(rh * 8 + r8) * 8 + bb] =
                  fmaf(w, av[bb], acc[(rh * 8 + r8) * 8 + bb]);
          }
        }
      }
      if (g < 3) {
#pragma unroll
        for (int cc = 0; cc < 4; ++cc) {
          a_cur[cc][0] = a_nxt[cc][0];
          a_cur[cc][1] = a_nxt[cc][1];
        }
      }
    }

    // ---- exchange-and-halve reduction over lane bits 3..5 ----
    const int lane = tid & 63;
    const bool b3 = (lane & 8) != 0;
    const bool b4 = (lane & 16) != 0;
    const bool b5 = (lane & 32) != 0;
    float v1[64];
#pragma unroll
    for (int go = 0; go < 8; ++go)
#pragma unroll
      for (int j = 0; j < 8; ++j) {
        float lc = acc[(2 * go + 0) * 8 + j];
        float hc = acc[(2 * go + 1) * 8 + j];
        float lo_o = __shfl_xor(lc, 8, 64);
        float hi_o = __shfl_xor(hc, 8, 64);
        v1[go * 8 + j] = b3 ? (hc + hi_o) : (lc + lo_o);
      }
    float v2[32];
#pragma unroll
    for (int go = 0; go < 4; ++go)
#pragma unroll
      for (int j = 0; j < 8; ++j) {
        float lc = v1[(2 * go + 0) * 8 + j];
        float hc = v1[(2 * go + 1) * 8 + j];
        float lo_o = __shfl_xor(lc, 16, 64);
        float hi_o = __shfl_xor(hc, 16, 64);
        v2[go * 8 + j] = b4 ? (hc + hi_o) : (lc + lo_o);
      }
    float fin[16];
#pragma unroll
    for (int go = 0; go < 2; ++go)
#pragma unroll
      for (int j = 0; j < 8; ++j) {
        float lc = v2[(2 * go + 0) * 8 + j];
        float hc = v2[(2 * go + 1) * 8 + j];
        float lo_o = __shfl_xor(lc, 32, 64);
        float hi_o = __shfl_xor(hc, 32, 64);
        fin[go * 8 + j] = b5 ? (hc + hi_o) : (lc + lo_o);
      }
    // lane holds rows {sigma, 8+sigma} for b = tb*8 + j
    const int wv = tid >> 6;
    const int sigma = (lane >> 3) & 7;
    float* dst0 = s_red + wv * 1024 + sigma * 64 + tb * 8;
    *reinterpret_cast<float4*>(dst0) =
        make_float4(fin[0], fin[1], fin[2], fin[3]);
    *reinterpret_cast<float4*>(dst0 + 4) =
        make_float4(fin[4], fin[5], fin[6], fin[7]);
    float* dst1 = dst0 + 512;  // rows 8+sigma
    *reinterpret_cast<float4*>(dst1) =
        make_float4(fin[8], fin[9], fin[10], fin[11]);
    *reinterpret_cast<float4*>(dst1 + 4) =
        make_float4(fin[12], fin[13], fin[14], fin[15]);
    __syncthreads();
    {
      const float* bsum_l = g_ws + OFF_BSUM + layer * 2048;
#pragma unroll
      for (int h2 = 0; h2 < 2; ++h2) {
        int o = h2 * 512 + tid;
        float sum = 0.f;
#pragma unroll
        for (int w8 = 0; w8 < 8; ++w8) sum += s_red[w8 * 1024 + o];
        int r = o >> 6;
        int grow = (r >> 2) * 512 + lid * 4 + (r & 3);
        s_g[o] = sum + bsum_l[grow];  // s_g[r*64 + b]
      }
    }
    __syncthreads();
  };

  float cs = 0.f;  // tid<256 owns cell state (col = lid*4 + (tid>>6), b)

  auto cell_update = [&](float* dst) {
    if (tid < 256) {
      const int j = tid >> 6, b = tid & 63, col = lid * 4 + j;
      float ig = sigm(s_g[j * 64 + b]);
      float fg = sigm(s_g[(4 + j) * 64 + b]);
      float gt = tanh_fast(s_g[(8 + j) * 64 + b]);
      float og = sigm(s_g[(12 + j) * 64 + b]);
      cs = fg * cs + ig * gt;
      coh_store1(dst + col * 64 + b, og * tanh_fast(cs));
    }
  };

  // ---- inp(tn) = sigmoid(x[tn] @ w_in^T + b_in) -> cols lid*4..+3 ----
  auto inp_block = [&](int tn, int slot) {
    const int b = tid & 63, jj = (tid >> 6) & 3, kh = tid >> 8;
    const int col = lid * 4 + jj;
    const float* xsrc = x + ((size_t)tn * B + b) * I_DIM + kh * 64;
    const float* wrow = w_in + (size_t)col * I_DIM + kh * 64;
    float part = 0.f;
#pragma unroll
    for (int k4 = 0; k4 < 16; ++k4) {
      float4 xv = *reinterpret_cast<const float4*>(xsrc + k4 * 4);
      float4 wv = *reinterpret_cast<const float4*>(wrow + k4 * 4);
      part += xv.x * wv.x + xv.y * wv.y + xv.z * wv.z + xv.w * wv.w;
    }
    s_red[tid] = part;
    __syncthreads();
    if (tid < 256) {
      float v = s_red[tid] + s_red[tid + 256];
      const int jj2 = (tid >> 6) & 3, b2 = tid & 63;
      const int col2 = lid * 4 + jj2;
      coh_store1(g_ws + OFF_INP + (size_t)slot * HB + col2 * 64 + b2,
                 sigm(v + b_in[col2]));
    }
    __syncthreads();
  };

  // ---- out(tt): gather h1 column b into LDS once, then reduce ----
  auto out_block = [&](int tt, int slot) {
    const int b = lid >> 1, ihalf = lid & 1;
    s_h1[tid] = g_ws[OFF_H1 + (size_t)slot * HB + tid * 64 + b];  // cached
    __syncthreads();
    const int io = tid & 63, ks = tid >> 6;  // ks 0..7, 64 k each
    const int i = ihalf * 64 + io;
    const float* wrow = w_out + (size_t)i * H + ks * 64;
    const float* hl = s_h1 + ks * 64;  // broadcast across io lanes
    float part = 0.f;
#pragma unroll
    for (int k4 = 0; k4 < 16; ++k4) {
      float4 wv = *reinterpret_cast<const float4*>(wrow + k4 * 4);
      part += wv.x * hl[k4 * 4 + 0] + wv.y * hl[k4 * 4 + 1] +
              wv.z * hl[k4 * 4 + 2] + wv.w * hl[k4 * 4 + 3];
    }
    s_red[tid] = part;
    __syncthreads();
    if (tid < 64) {
      float sum = 0.f;
#pragma unroll
      for (int kk = 0; kk < 8; ++kk) sum += s_red[kk * 64 + tid];
      const int ii = ihalf * 64 + tid;
      coh_store1(out + ((size_t)tt * B + b) * I_DIM + ii, sum + b_out[ii]);
    }
    __syncthreads();
  };

  // ---------------- prologue: inp(0), inp(1); barrier B0 (inv) ----------
  // (no g_ws READS before B0: B0's inv kills prior-dispatch stale lines)
  if (layer == 0) {
    inp_block(0, 0);
    inp_block(1, 1);
  }
  bar_arrive(true);  // B0: inv barrier
  bar_wait();

  // ---------------- pipelined main loop: one barrier per tick -----------
  // tick tau: L0 computes h0(tau); L1 computes h1(tau-1). Window work
  // (between arrive and wait): L0 writes inp(tau+2), L1 writes out(tau-2).
  // Barrier after tick tau is B_{tau+1}; inv when (tau+1)%7==0.
  for (int tau = 0; tau <= T_STEPS + 1; ++tau) {
    const int sl = tau & 7;
    const float* glo;
    const float* ghi;
    float* gdst;
    bool do_g;
    if (layer == 0) {
      glo = g_ws + OFF_INP + (size_t)sl * HB;                  // inp(tau)
      ghi = g_ws + OFF_H0 + (size_t)((tau - 1) & 7) * HB;      // h0(tau-1)
      gdst = g_ws + OFF_H0 + (size_t)sl * HB;                  // h0(tau)
      do_g = (tau < T_STEPS);
    } else {
      glo = g_ws + OFF_H0 + (size_t)((tau - 1) & 7) * HB;      // h0(tau-1)
      ghi = g_ws + OFF_H1 + (size_t)((tau - 2) & 7) * HB;      // h1(tau-2)
      gdst = g_ws + OFF_H1 + (size_t)((tau - 1) & 7) * HB;     // h1(tau-1)
      do_g = (tau >= 1 && tau <= T_STEPS);
    }
    if (do_g) {
      gemv(glo, ghi);
      cell_update(gdst);
    }
    if (tau <= T_STEPS) {
      bar_arrive(((tau + 1) % 7) == 0);
      // ---- window work (post-arrival, pre-release) ----
      if (layer == 0) {
        if (tau + 2 <= T_STEPS - 1) inp_block(tau + 2, (tau + 2) & 7);
      } else {
        if (tau >= 2) out_block(tau - 2, (tau - 2) & 7);
      }
      bar_wait();
    } else {
      // final tick (tau == T_STEPS+1): no barrier; L1 emits last output
      if (layer == 1) out_block(tau - 2, (tau - 2) & 7);
    }
  }
}

extern "C" void kernel_launch(void* const* d_in, const int* in_sizes, int n_in,
                              void* d_out, int out_size, void* d_ws,
                              size_t ws_size, hipStream_t stream) {
  const float* x     = (const float*)d_in[0];
  const float* w_in  = (const float*)d_in[1];
  const float* b_in  = (const float*)d_in[2];
  const float* w_ih  = (const float*)d_in[3];
  const float* w_hh  = (const float*)d_in[4];
  const float* b_ih  = (const float*)d_in[5];
  const float* b_hh  = (const float*)d_in[6];
  const float* w_out = (const float*)d_in[7];
  const float* b_out = (const float*)d_in[8];
  float* outp = (float*)d_out;
  (void)d_ws;  // workspace moved to __device__ g_ws (L2-cacheable)
  (void)ws_size;

  hipLaunchKernelGGL(init_ws_kernel, dim3(NBLK), dim3(NTHR), 0, stream,
                     b_ih, b_hh);
  hipLaunchKernelGGL(lstm_kernel, dim3(NBLK), dim3(NTHR), 0, stream, x, w_in,
                     b_in, w_ih, w_hh, w_out, b_out, outp);
}